// Round 8
// baseline (177.390 us; speedup 1.0000x reference)
//
#include <hip/hip_runtime.h>
#include <math.h>

#define NP 50000
#define HIDDEN 256
#define NE 800000
#define CAP 64          // ELL capacity; P(Poisson(16) > 64) ~ 1e-20

#define NSLICE 8
#define SLICE_ROWS 6250            // NP / NSLICE
#define BPS 256                    // scatter blocks per slice

#define PWB 2048                   // persistent-wave blocks (8/CU)
#define PWAVES (PWB * 4)           // 8192 waves

// workspace layout (bytes)
#define OFF_AH     0ULL           // [P][256] bf16 : AH
#define OFF_A2H    25600000ULL    // [P][256] bf16 : A2H
#define OFF_BP     51200000ULL    // Bp [64][256][8] bf16 packed weights
#define OFF_CNT    51462144ULL    // per-row edge count [P] int
#define OFF_PC     51662144ULL    // packed (beta,degree) [P] float2
#define OFF_EV     52062144ULL    // ELL edges (col, val-bits) [P][CAP] int2

typedef __attribute__((ext_vector_type(8))) short bf16x8;
typedef __attribute__((ext_vector_type(8))) unsigned short u16x8;
typedef __attribute__((ext_vector_type(4))) float f32x4;

__device__ inline unsigned short f2bf(float f) {
    union { float f; unsigned int u; } x; x.f = f;
    unsigned int r = x.u + 0x7FFFu + ((x.u >> 16) & 1u);   // RNE
    return (unsigned short)(r >> 16);
}
__device__ inline float bf2f(unsigned short u) {
    union { unsigned int u; float f; } x; x.u = ((unsigned int)u) << 16; return x.f;
}

// ---------------- fused prep: Bp pack | pc pack | cnt zero ----------------
// blocks [0,512): Bp[k>>3][col][k&7] = Wcat[col][k]
// blocks [512,708): pc[i] = (beta[i], degree[i])
// blocks [708,904): cnt[i] = 0
__global__ void prep_kernel(const float* __restrict__ W1,
                            const float* __restrict__ W2,
                            unsigned short* __restrict__ Bp,
                            const float* __restrict__ beta,
                            const float* __restrict__ degree,
                            float2* __restrict__ pc,
                            int* __restrict__ cnt) {
    int b = blockIdx.x;
    if (b < 512) {
        int t = b * 256 + threadIdx.x;
        int j = t >> 9;
        int k = t & 511;
        float v = (k < 256) ? W1[j * 256 + k] : W2[j * 256 + (k - 256)];
        Bp[(k >> 3) * 2048 + j * 8 + (k & 7)] = f2bf(v);
    } else if (b < 708) {
        int i = (b - 512) * 256 + threadIdx.x;
        if (i < NP) pc[i] = make_float2(beta[i], degree[i]);
    } else {
        int i = (b - 708) * 256 + threadIdx.x;
        if (i < NP) cnt[i] = 0;
    }
}

// ---------------- XCD-sliced ELL scatter ----------------
// slice = blockIdx % 8 -> round-robin dispatch keeps a slice's ev region (3.2 MB)
// in one XCD's L2 so edge writes coalesce into full lines (perf heuristic only).
__global__ __launch_bounds__(256) void scatter_sliced(
        const int* __restrict__ rows, const int* __restrict__ cols,
        const float* __restrict__ vals,
        int* __restrict__ cnt, int2* __restrict__ ev) {
    int slice = blockIdx.x & (NSLICE - 1);
    int bj = blockIdx.x >> 3;
    int rlo = slice * SLICE_ROWS;
    int rhi = rlo + SLICE_ROWS;
    for (int e = bj * 256 + threadIdx.x; e < NE; e += BPS * 256) {
        int r = rows[e];
        if (r >= rlo && r < rhi) {
            int pos = atomicAdd(&cnt[r], 1);
            if (pos < CAP)
                ev[(size_t)r * CAP + pos] = make_int2(cols[e], __float_as_int(vals[e]));
        }
    }
}

// ---------------- hop 1 fused: AH[r] = sum_e val * relu(W_in . x[col] + b_in) ----------------
// persistent waves; next row's (cnt, ev) prefetched during current row's compute.
// ev loaded unconditionally: lanes >= n hold garbage but are never shuffle sources.
__global__ __launch_bounds__(256) void spmm_embed_kernel(
        const int* __restrict__ cnt, const int2* __restrict__ ev,
        const float2* __restrict__ pc,
        const float* __restrict__ W_in, const float* __restrict__ b_in,
        unsigned short* __restrict__ Y) {
    int w = threadIdx.x >> 6;
    int lane = threadIdx.x & 63;
    int half = lane >> 5;
    int fo = (lane & 31) * 8;

    float wr0[8], wr1[8], wr2[8], br[8];
    #pragma unroll
    for (int j = 0; j < 8; ++j) {
        wr0[j] = W_in[(fo + j) * 3 + 0];
        wr1[j] = W_in[(fo + j) * 3 + 1];
        wr2[j] = W_in[(fo + j) * 3 + 2];
        br[j]  = b_in[fo + j];
    }

    int r = blockIdx.x * 4 + w;
    if (r >= NP) return;
    int  n_cur = cnt[r];
    int2 e_cur = ev[(size_t)r * CAP + lane];

    while (true) {
        int rn = r + PWAVES;
        int  n_nxt = 0;
        int2 e_nxt = make_int2(0, 0);
        if (rn < NP) {                      // issued before compute -> prefetch
            n_nxt = cnt[rn];
            e_nxt = ev[(size_t)rn * CAP + lane];
        }

        int n = min(n_cur, CAP);
        int col_l = e_cur.x;
        float val_l = __int_as_float(e_cur.y);
        float acc[8] = {0.f,0.f,0.f,0.f,0.f,0.f,0.f,0.f};

#define ESTEP(MASKED)                                                        \
    {                                                                        \
        float2 pr[4]; float vr[4];                                           \
        _Pragma("unroll")                                                    \
        for (int k = 0; k < 4; ++k) {                                        \
            int e = i + 2 * k + half;                                        \
            int es = (MASKED) ? ((e < n) ? e : 0) : e;                       \
            int c = __shfl(col_l, es);                                       \
            float vt = __shfl(val_l, es);                                    \
            if (MASKED) vt = (e < n) ? vt : 0.f;                             \
            vr[k] = vt;                                                      \
            pr[k] = pc[c];                                                   \
        }                                                                    \
        _Pragma("unroll")                                                    \
        for (int k = 0; k < 4; ++k) {                                        \
            float b = pr[k].x, dd = pr[k].y, v = vr[k];                      \
            float b2 = b * b;                                                \
            _Pragma("unroll")                                                \
            for (int j = 0; j < 8; ++j) {                                    \
                float t = fmaf(b, wr0[j], fmaf(b2, wr1[j], fmaf(dd, wr2[j], br[j]))); \
                acc[j] = fmaf(v, fmaxf(t, 0.f), acc[j]);                     \
            }                                                                \
        }                                                                    \
    }

        int i = 0;
        for (; i + 8 <= n; i += 8) ESTEP(false)
        if (i < n) ESTEP(true)
#undef ESTEP

        #pragma unroll
        for (int j = 0; j < 8; ++j) acc[j] += __shfl_xor(acc[j], 32);
        if (half == 0) {
            u16x8 o;
            #pragma unroll
            for (int j = 0; j < 8; ++j) o[j] = f2bf(acc[j]);
            *reinterpret_cast<u16x8*>(Y + (size_t)r * HIDDEN + fo) = o;
        }

        if (rn >= NP) break;
        r = rn; n_cur = n_nxt; e_cur = e_nxt;
    }
}

// ---------------- hop 2: gather SpMM, persistent waves + prefetch ----------------
__global__ __launch_bounds__(256) void spmm_gather_kernel(
        const int* __restrict__ cnt, const int2* __restrict__ ev,
        const unsigned short* __restrict__ X,
        unsigned short* __restrict__ Y) {
    int w = threadIdx.x >> 6;
    int lane = threadIdx.x & 63;
    int half = lane >> 5;
    int fo = (lane & 31) * 8;

    int r = blockIdx.x * 4 + w;
    if (r >= NP) return;
    int  n_cur = cnt[r];
    int2 e_cur = ev[(size_t)r * CAP + lane];

    while (true) {
        int rn = r + PWAVES;
        int  n_nxt = 0;
        int2 e_nxt = make_int2(0, 0);
        if (rn < NP) {
            n_nxt = cnt[rn];
            e_nxt = ev[(size_t)rn * CAP + lane];
        }

        int n = min(n_cur, CAP);
        int col_l = e_cur.x;
        float val_l = __int_as_float(e_cur.y);
        float acc[8] = {0.f,0.f,0.f,0.f,0.f,0.f,0.f,0.f};

#define GSTEP(MASKED)                                                        \
    {                                                                        \
        u16x8 xr[4]; float vr[4];                                            \
        _Pragma("unroll")                                                    \
        for (int k = 0; k < 4; ++k) {                                        \
            int e = i + 2 * k + half;                                        \
            int es = (MASKED) ? ((e < n) ? e : 0) : e;                       \
            int c = __shfl(col_l, es);                                       \
            float vt = __shfl(val_l, es);                                    \
            if (MASKED) vt = (e < n) ? vt : 0.f;                             \
            vr[k] = vt;                                                      \
            xr[k] = *reinterpret_cast<const u16x8*>(X + (size_t)c * HIDDEN + fo); \
        }                                                                    \
        _Pragma("unroll")                                                    \
        for (int k = 0; k < 4; ++k)                                          \
            _Pragma("unroll")                                                \
            for (int j = 0; j < 8; ++j)                                      \
                acc[j] = fmaf(vr[k], bf2f(xr[k][j]), acc[j]);                \
    }

        int i = 0;
        for (; i + 8 <= n; i += 8) GSTEP(false)
        if (i < n) GSTEP(true)
#undef GSTEP

        #pragma unroll
        for (int j = 0; j < 8; ++j) acc[j] += __shfl_xor(acc[j], 32);
        if (half == 0) {
            u16x8 o;
            #pragma unroll
            for (int j = 0; j < 8; ++j) o[j] = f2bf(acc[j]);
            *reinterpret_cast<u16x8*>(Y + (size_t)r * HIDDEN + fo) = o;
        }

        if (rn >= NP) break;
        r = rn; n_cur = n_nxt; e_cur = e_nxt;
    }
}

// ---------------- fused MP GEMM (MFMA bf16) + relu + out-proj + softplus ----------------
// block: 512 threads = 8 waves; tile 128 rows x 256 cols; K = 512 in 8 chunks of 64
// K-chunks 0..3 read AH, 4..7 read A2H (both compact [P][256])
__global__ __launch_bounds__(512, 4) void mp_out_kernel(
        const unsigned short* __restrict__ AH,
        const unsigned short* __restrict__ A2H,
        const unsigned short* __restrict__ Bp,
        const float* __restrict__ W_out, const float* __restrict__ b_out,
        float* __restrict__ g) {
    __shared__ unsigned short As[128 * 64];    // 16 KB, XOR-swizzled
    __shared__ unsigned short Bs[8 * 256 * 8]; // 32 KB, [kbl][col][8]
    __shared__ float Ps[4][128];               // 2 KB partials

    int tid = threadIdx.x;
    int w = tid >> 6;
    int lane = tid & 63;
    int wr = w >> 2;
    int wc = w & 3;
    int p0 = blockIdx.x * 128;

    f32x4 acc[4][4];
    #pragma unroll
    for (int i = 0; i < 4; ++i)
        #pragma unroll
        for (int j = 0; j < 4; ++j)
            acc[i][j] = (f32x4){0.f, 0.f, 0.f, 0.f};

    for (int kc = 0; kc < 8; ++kc) {
        const unsigned short* Xsrc = (kc < 4) ? AH : A2H;
        int k0 = (kc & 3) * 64;
        __syncthreads();
        // stage A: 1024 x 16B slots. LDS[slot] = A_global[slot ^ swz(row)] (both-sides swizzle)
        #pragma unroll
        for (int it = 0; it < 2; ++it) {
            int slot = it * 512 + tid;
            int ss = slot ^ ((slot >> 3) & 7);         // involution, row bits untouched
            int row = ss >> 3;
            int ko = (ss & 7) * 8;
            int grow = p0 + row;
            if (grow >= NP) grow = NP - 1;
            float4 v = *reinterpret_cast<const float4*>(Xsrc + (size_t)grow * HIDDEN + k0 + ko);
            *reinterpret_cast<float4*>(&As[slot * 8]) = v;
        }
        // stage B: 2048 x 16B chunks, linear
        #pragma unroll
        for (int it = 0; it < 4; ++it) {
            int c2 = it * 512 + tid;
            float4 v = *reinterpret_cast<const float4*>(
                Bp + ((size_t)(kc * 8 + (c2 >> 8))) * 2048 + (c2 & 255) * 8);
            *reinterpret_cast<float4*>(&Bs[c2 * 8]) = v;
        }
        __syncthreads();
        #pragma unroll
        for (int ks = 0; ks < 2; ++ks) {
            bf16x8 af[4], bfr[4];
            #pragma unroll
            for (int rt = 0; rt < 4; ++rt) {
                int row = wr * 64 + rt * 16 + (lane & 15);
                int elem = row * 64 + ks * 32 + (lane >> 4) * 8;
                elem ^= (row & 7) << 3;                // matches staging swizzle
                af[rt] = *reinterpret_cast<const bf16x8*>(&As[elem]);
            }
            #pragma unroll
            for (int nt = 0; nt < 4; ++nt) {
                int col = wc * 64 + nt * 16 + (lane & 15);
                int kbl = ks * 4 + (lane >> 4);
                bfr[nt] = *reinterpret_cast<const bf16x8*>(&Bs[kbl * 2048 + col * 8]);
            }
            #pragma unroll
            for (int rt = 0; rt < 4; ++rt)
                #pragma unroll
                for (int nt = 0; nt < 4; ++nt)
                    acc[rt][nt] = __builtin_amdgcn_mfma_f32_16x16x32_bf16(
                        af[rt], bfr[nt], acc[rt][nt], 0, 0, 0);
        }
    }

    // epilogue: relu -> dot W_out (this wave's 64 cols) -> LDS partial
    float wv[4];
    #pragma unroll
    for (int nt = 0; nt < 4; ++nt)
        wv[nt] = W_out[wc * 64 + nt * 16 + (lane & 15)];

    float ps[4][4];
    #pragma unroll
    for (int rt = 0; rt < 4; ++rt)
        #pragma unroll
        for (int r = 0; r < 4; ++r) {
            float s = 0.f;
            #pragma unroll
            for (int nt = 0; nt < 4; ++nt)
                s = fmaf(fmaxf(acc[rt][nt][r], 0.0f), wv[nt], s);
            ps[rt][r] = s;
        }
    #pragma unroll
    for (int m = 1; m < 16; m <<= 1)
        #pragma unroll
        for (int rt = 0; rt < 4; ++rt)
            #pragma unroll
            for (int r = 0; r < 4; ++r)
                ps[rt][r] += __shfl_xor(ps[rt][r], m);

    if ((lane & 15) == 0) {
        int rb = wr * 64 + (lane >> 4) * 4;
        #pragma unroll
        for (int rt = 0; rt < 4; ++rt)
            #pragma unroll
            for (int r = 0; r < 4; ++r)
                Ps[wc][rb + rt * 16 + r] = ps[rt][r];
    }
    __syncthreads();
    if (tid < 128) {
        int p = p0 + tid;
        if (p < NP) {
            float z = Ps[0][tid] + Ps[1][tid] + Ps[2][tid] + Ps[3][tid] + b_out[0];
            g[p] = fmaxf(z, 0.0f) + log1pf(expf(-fabsf(z)));
        }
    }
}

extern "C" void kernel_launch(void* const* d_in, const int* in_sizes, int n_in,
                              void* d_out, int out_size, void* d_ws, size_t ws_size,
                              hipStream_t stream) {
    const float* beta   = (const float*)d_in[0];
    const float* degree = (const float*)d_in[1];
    const int*   A_rows = (const int*)d_in[2];
    const int*   A_cols = (const int*)d_in[3];
    const float* A_vals = (const float*)d_in[4];
    const float* W_in   = (const float*)d_in[5];
    const float* b_in   = (const float*)d_in[6];
    const float* W_mp1  = (const float*)d_in[7];
    const float* W_mp2  = (const float*)d_in[8];
    const float* W_out  = (const float*)d_in[9];
    const float* b_out  = (const float*)d_in[10];
    float* g = (float*)d_out;

    char* ws = (char*)d_ws;
    unsigned short* AH  = (unsigned short*)(ws + OFF_AH);
    unsigned short* A2H = (unsigned short*)(ws + OFF_A2H);
    unsigned short* Bp  = (unsigned short*)(ws + OFF_BP);
    int*    cnt = (int*)(ws + OFF_CNT);
    float2* pc  = (float2*)(ws + OFF_PC);
    int2*   ev  = (int2*)(ws + OFF_EV);

    // prep: Bp pack | pc pack | cnt zero (one launch)
    prep_kernel<<<904, 256, 0, stream>>>(W_mp1, W_mp2, Bp, beta, degree, pc, cnt);

    // XCD-sliced ELL scatter
    scatter_sliced<<<NSLICE * BPS, 256, 0, stream>>>(A_rows, A_cols, A_vals, cnt, ev);

    // AH = A @ relu(x W_in^T + b_in)   (h recomputed per edge; persistent waves)
    spmm_embed_kernel<<<PWB, 256, 0, stream>>>(cnt, ev, pc, W_in, b_in, AH);
    // A2H = A @ AH                      (persistent waves)
    spmm_gather_kernel<<<PWB, 256, 0, stream>>>(cnt, ev, AH, A2H);

    mp_out_kernel<<<(NP + 127) / 128, 512, 0, stream>>>(AH, A2H, Bp, W_out, b_out, g);
}

// Round 9
// 161.204 us; speedup vs baseline: 1.1004x; 1.1004x over previous
//
#include <hip/hip_runtime.h>
#include <math.h>

#define NP 50000
#define HIDDEN 256
#define NE 800000
#define CAP 64          // ELL capacity; P(Poisson(16) > 64) ~ 1e-20

#define NSLICE 8
#define SLICE_ROWS 6250            // NP / NSLICE
#define BPS 256                    // scatter blocks per slice

// workspace layout (bytes)
#define OFF_AH     0ULL           // [P][256] bf16 : AH
#define OFF_A2H    25600000ULL    // [P][256] bf16 : A2H
#define OFF_BP     51200000ULL    // Bp [64][256][8] bf16 packed weights
#define OFF_CNT    51462144ULL    // per-row edge count [P] int
#define OFF_PC     51662144ULL    // packed (beta,degree) [P] float2
#define OFF_EV     52062144ULL    // ELL edges (col, val-bits) [P][CAP] int2

typedef __attribute__((ext_vector_type(8))) short bf16x8;
typedef __attribute__((ext_vector_type(8))) unsigned short u16x8;
typedef __attribute__((ext_vector_type(4))) float f32x4;

__device__ inline unsigned short f2bf(float f) {
    union { float f; unsigned int u; } x; x.f = f;
    unsigned int r = x.u + 0x7FFFu + ((x.u >> 16) & 1u);   // RNE
    return (unsigned short)(r >> 16);
}
__device__ inline float bf2f(unsigned short u) {
    union { unsigned int u; float f; } x; x.u = ((unsigned int)u) << 16; return x.f;
}

// async global->LDS 16B: per-lane global src, wave-uniform LDS base (+lane*16)
__device__ __forceinline__ void gload16(const void* g, void* l) {
    __builtin_amdgcn_global_load_lds(
        (const __attribute__((address_space(1))) unsigned int*)g,
        (__attribute__((address_space(3))) unsigned int*)l, 16, 0, 0);
}

// ---------------- fused prep: Bp pack | pc pack | cnt zero ----------------
__global__ void prep_kernel(const float* __restrict__ W1,
                            const float* __restrict__ W2,
                            unsigned short* __restrict__ Bp,
                            const float* __restrict__ beta,
                            const float* __restrict__ degree,
                            float2* __restrict__ pc,
                            int* __restrict__ cnt) {
    int b = blockIdx.x;
    if (b < 512) {
        int t = b * 256 + threadIdx.x;
        int j = t >> 9;
        int k = t & 511;
        float v = (k < 256) ? W1[j * 256 + k] : W2[j * 256 + (k - 256)];
        Bp[(k >> 3) * 2048 + j * 8 + (k & 7)] = f2bf(v);
    } else if (b < 708) {
        int i = (b - 512) * 256 + threadIdx.x;
        if (i < NP) pc[i] = make_float2(beta[i], degree[i]);
    } else {
        int i = (b - 708) * 256 + threadIdx.x;
        if (i < NP) cnt[i] = 0;
    }
}

// ---------------- XCD-sliced ELL scatter ----------------
// slice = blockIdx % 8 -> round-robin dispatch keeps a slice's ev region (3.2 MB)
// in one XCD's L2 (perf heuristic only; correct under any mapping).
__global__ __launch_bounds__(256) void scatter_sliced(
        const int* __restrict__ rows, const int* __restrict__ cols,
        const float* __restrict__ vals,
        int* __restrict__ cnt, int2* __restrict__ ev) {
    int slice = blockIdx.x & (NSLICE - 1);
    int bj = blockIdx.x >> 3;
    int rlo = slice * SLICE_ROWS;
    int rhi = rlo + SLICE_ROWS;
    for (int e0 = (bj * 256 + threadIdx.x) * 4; e0 < NE; e0 += BPS * 256 * 4) {
        int4 r4 = *reinterpret_cast<const int4*>(rows + e0);
        #pragma unroll
        for (int q = 0; q < 4; ++q) {
            int r = (q == 0) ? r4.x : (q == 1) ? r4.y : (q == 2) ? r4.z : r4.w;
            if (r >= rlo && r < rhi) {
                int e = e0 + q;
                int pos = atomicAdd(&cnt[r], 1);
                if (pos < CAP)
                    ev[(size_t)r * CAP + pos] = make_int2(cols[e], __float_as_int(vals[e]));
            }
        }
    }
}

// ---------------- hop 1 fused: AH[r] = sum_e val * relu(W_in . x[col] + b_in) ----------------
__global__ __launch_bounds__(256) void spmm_embed_kernel(
        const int* __restrict__ cnt, const int2* __restrict__ ev,
        const float2* __restrict__ pc,
        const float* __restrict__ W_in, const float* __restrict__ b_in,
        unsigned short* __restrict__ Y) {
    int w = threadIdx.x >> 6;
    int lane = threadIdx.x & 63;
    int r = blockIdx.x * 4 + w;
    if (r >= NP) return;
    int half = lane >> 5;
    int fo = (lane & 31) * 8;

    int n = min(cnt[r], CAP);
    int2 e2 = make_int2(0, 0);                 // val 0 beyond n -> padded steps harmless
    if (lane < n) e2 = ev[(size_t)r * CAP + lane];
    int col_l = e2.x;
    float val_l = __int_as_float(e2.y);

    float wr0[8], wr1[8], wr2[8], br[8];
    #pragma unroll
    for (int j = 0; j < 8; ++j) {
        wr0[j] = W_in[(fo + j) * 3 + 0];
        wr1[j] = W_in[(fo + j) * 3 + 1];
        wr2[j] = W_in[(fo + j) * 3 + 2];
        br[j]  = b_in[fo + j];
    }

    float acc[8] = {0.f,0.f,0.f,0.f,0.f,0.f,0.f,0.f};

#define ESTEP(d)                                                             \
    {                                                                        \
        float2 pr[d]; float vr[d];                                           \
        _Pragma("unroll")                                                    \
        for (int k = 0; k < (d); ++k) {                                      \
            int e = i + 2 * k + half;                                        \
            int c = __shfl(col_l, e);                                        \
            vr[k] = __shfl(val_l, e);                                        \
            pr[k] = pc[c];                                                   \
        }                                                                    \
        _Pragma("unroll")                                                    \
        for (int k = 0; k < (d); ++k) {                                      \
            float b = pr[k].x, dd = pr[k].y, v = vr[k];                      \
            float b2 = b * b;                                                \
            _Pragma("unroll")                                                \
            for (int j = 0; j < 8; ++j) {                                    \
                float t = fmaf(b, wr0[j], fmaf(b2, wr1[j], fmaf(dd, wr2[j], br[j]))); \
                acc[j] = fmaf(v, fmaxf(t, 0.f), acc[j]);                     \
            }                                                                \
        }                                                                    \
    }

    int i = 0;
    for (; i + 16 <= n; i += 16) ESTEP(8)
    if (i + 8 <= n) { ESTEP(4) i += 8; }
    if (i + 4 <= n) { ESTEP(2) i += 4; }
    if (i < n) {
        float2 pr[2]; float vr[2];
        #pragma unroll
        for (int k = 0; k < 2; ++k) {
            int e = i + 2 * k + half;
            int es = (e < n) ? e : 0;
            int c = __shfl(col_l, es);
            float vt = __shfl(val_l, es);
            vr[k] = (e < n) ? vt : 0.f;
            pr[k] = pc[c];
        }
        #pragma unroll
        for (int k = 0; k < 2; ++k) {
            float b = pr[k].x, dd = pr[k].y, v = vr[k];
            float b2 = b * b;
            #pragma unroll
            for (int j = 0; j < 8; ++j) {
                float t = fmaf(b, wr0[j], fmaf(b2, wr1[j], fmaf(dd, wr2[j], br[j])));
                acc[j] = fmaf(v, fmaxf(t, 0.f), acc[j]);
            }
        }
    }
#undef ESTEP

    #pragma unroll
    for (int j = 0; j < 8; ++j) acc[j] += __shfl_xor(acc[j], 32);
    if (half == 0) {
        u16x8 o;
        #pragma unroll
        for (int j = 0; j < 8; ++j) o[j] = f2bf(acc[j]);
        *reinterpret_cast<u16x8*>(Y + (size_t)r * HIDDEN + fo) = o;
    }
}

// ---------------- hop 2: gather SpMM, adaptive depth ladder (r7 form) ----------------
__global__ __launch_bounds__(256) void spmm_gather_kernel(
        const int* __restrict__ cnt, const int2* __restrict__ ev,
        const unsigned short* __restrict__ X,
        unsigned short* __restrict__ Y) {
    int w = threadIdx.x >> 6;
    int lane = threadIdx.x & 63;
    int r = blockIdx.x * 4 + w;
    if (r >= NP) return;
    int half = lane >> 5;
    int fo = (lane & 31) * 8;

    int n = min(cnt[r], CAP);
    int2 e2 = make_int2(0, 0);
    if (lane < n) e2 = ev[(size_t)r * CAP + lane];
    int col_l = e2.x;
    float val_l = __int_as_float(e2.y);

    float acc[8] = {0.f,0.f,0.f,0.f,0.f,0.f,0.f,0.f};

#define GSTEP(d)                                                             \
    {                                                                        \
        u16x8 xr[d]; float vr[d];                                            \
        _Pragma("unroll")                                                    \
        for (int k = 0; k < (d); ++k) {                                      \
            int e = i + 2 * k + half;                                        \
            int c = __shfl(col_l, e);                                        \
            vr[k] = __shfl(val_l, e);                                        \
            xr[k] = *reinterpret_cast<const u16x8*>(X + (size_t)c * HIDDEN + fo); \
        }                                                                    \
        _Pragma("unroll")                                                    \
        for (int k = 0; k < (d); ++k)                                        \
            _Pragma("unroll")                                                \
            for (int j = 0; j < 8; ++j)                                      \
                acc[j] = fmaf(vr[k], bf2f(xr[k][j]), acc[j]);                \
    }

    int i = 0;
    for (; i + 16 <= n; i += 16) GSTEP(8)
    if (i + 8 <= n) { GSTEP(4) i += 8; }
    if (i + 4 <= n) { GSTEP(2) i += 4; }
    if (i < n) {
        u16x8 xr[2]; float vr[2];
        #pragma unroll
        for (int k = 0; k < 2; ++k) {
            int e = i + 2 * k + half;
            int es = (e < n) ? e : 0;
            int c = __shfl(col_l, es);
            float vt = __shfl(val_l, es);
            vr[k] = (e < n) ? vt : 0.f;
            xr[k] = *reinterpret_cast<const u16x8*>(X + (size_t)c * HIDDEN + fo);
        }
        #pragma unroll
        for (int k = 0; k < 2; ++k)
            #pragma unroll
            for (int j = 0; j < 8; ++j)
                acc[j] = fmaf(vr[k], bf2f(xr[k][j]), acc[j]);
    }
#undef GSTEP

    #pragma unroll
    for (int j = 0; j < 8; ++j) acc[j] += __shfl_xor(acc[j], 32);
    if (half == 0) {
        u16x8 o;
        #pragma unroll
        for (int j = 0; j < 8; ++j) o[j] = f2bf(acc[j]);
        *reinterpret_cast<u16x8*>(Y + (size_t)r * HIDDEN + fo) = o;
    }
}

// ---------------- fused MP GEMM (MFMA bf16) + relu + out-proj + softplus ----------------
// block: 512 threads = 8 waves; tile 128 rows x 256 cols; K = 512 in 8 chunks of 64
// staging via global_load_lds (linear LDS dest + pre-swizzled global source)
__global__ __launch_bounds__(512, 4) void mp_out_kernel(
        const unsigned short* __restrict__ AH,
        const unsigned short* __restrict__ A2H,
        const unsigned short* __restrict__ Bp,
        const float* __restrict__ W_out, const float* __restrict__ b_out,
        float* __restrict__ g) {
    __shared__ unsigned short As[128 * 64];    // 16 KB, XOR-swizzled
    __shared__ unsigned short Bs[8 * 256 * 8]; // 32 KB, [kbl][col][8]
    __shared__ float Ps[4][128];               // 2 KB partials

    int tid = threadIdx.x;
    int w = tid >> 6;
    int lane = tid & 63;
    int wr = w >> 2;
    int wc = w & 3;
    int p0 = blockIdx.x * 128;

    f32x4 acc[4][4];
    #pragma unroll
    for (int i = 0; i < 4; ++i)
        #pragma unroll
        for (int j = 0; j < 4; ++j)
            acc[i][j] = (f32x4){0.f, 0.f, 0.f, 0.f};

    for (int kc = 0; kc < 8; ++kc) {
        const unsigned short* Xsrc = (kc < 4) ? AH : A2H;
        int k0 = (kc & 3) * 64;
        __syncthreads();
        // stage A: LDS[slot] = A_global[slot ^ swz] ; dest linear per wave (1KB/round)
        #pragma unroll
        for (int it = 0; it < 2; ++it) {
            int slot = it * 512 + tid;
            int ss = slot ^ ((slot >> 3) & 7);         // involution, row bits untouched
            int row = ss >> 3;
            int ko = (ss & 7) * 8;
            int grow = p0 + row;
            if (grow >= NP) grow = NP - 1;
            gload16(Xsrc + (size_t)grow * HIDDEN + k0 + ko,
                    &As[(size_t)(it * 512 + w * 64) * 8]);
        }
        // stage B: linear 16B chunks, perfectly coalesced
        #pragma unroll
        for (int it = 0; it < 4; ++it) {
            int c2 = it * 512 + tid;
            gload16(Bp + ((size_t)(kc * 8 + (c2 >> 8))) * 2048 + (c2 & 255) * 8,
                    &Bs[(size_t)(it * 512 + w * 64) * 8]);
        }
        __syncthreads();
        #pragma unroll
        for (int ks = 0; ks < 2; ++ks) {
            bf16x8 af[4], bfr[4];
            #pragma unroll
            for (int rt = 0; rt < 4; ++rt) {
                int row = wr * 64 + rt * 16 + (lane & 15);
                int elem = row * 64 + ks * 32 + (lane >> 4) * 8;
                elem ^= (row & 7) << 3;                // matches staging swizzle
                af[rt] = *reinterpret_cast<const bf16x8*>(&As[elem]);
            }
            #pragma unroll
            for (int nt = 0; nt < 4; ++nt) {
                int col = wc * 64 + nt * 16 + (lane & 15);
                int kbl = ks * 4 + (lane >> 4);
                bfr[nt] = *reinterpret_cast<const bf16x8*>(&Bs[kbl * 2048 + col * 8]);
            }
            #pragma unroll
            for (int rt = 0; rt < 4; ++rt)
                #pragma unroll
                for (int nt = 0; nt < 4; ++nt)
                    acc[rt][nt] = __builtin_amdgcn_mfma_f32_16x16x32_bf16(
                        af[rt], bfr[nt], acc[rt][nt], 0, 0, 0);
        }
    }

    // epilogue: relu -> dot W_out (this wave's 64 cols) -> LDS partial
    float wv[4];
    #pragma unroll
    for (int nt = 0; nt < 4; ++nt)
        wv[nt] = W_out[wc * 64 + nt * 16 + (lane & 15)];

    float ps[4][4];
    #pragma unroll
    for (int rt = 0; rt < 4; ++rt)
        #pragma unroll
        for (int r = 0; r < 4; ++r) {
            float s = 0.f;
            #pragma unroll
            for (int nt = 0; nt < 4; ++nt)
                s = fmaf(fmaxf(acc[rt][nt][r], 0.0f), wv[nt], s);
            ps[rt][r] = s;
        }
    #pragma unroll
    for (int m = 1; m < 16; m <<= 1)
        #pragma unroll
        for (int rt = 0; rt < 4; ++rt)
            #pragma unroll
            for (int r = 0; r < 4; ++r)
                ps[rt][r] += __shfl_xor(ps[rt][r], m);

    if ((lane & 15) == 0) {
        int rb = wr * 64 + (lane >> 4) * 4;
        #pragma unroll
        for (int rt = 0; rt < 4; ++rt)
            #pragma unroll
            for (int r = 0; r < 4; ++r)
                Ps[wc][rb + rt * 16 + r] = ps[rt][r];
    }
    __syncthreads();
    if (tid < 128) {
        int p = p0 + tid;
        if (p < NP) {
            float z = Ps[0][tid] + Ps[1][tid] + Ps[2][tid] + Ps[3][tid] + b_out[0];
            g[p] = fmaxf(z, 0.0f) + log1pf(expf(-fabsf(z)));
        }
    }
}

extern "C" void kernel_launch(void* const* d_in, const int* in_sizes, int n_in,
                              void* d_out, int out_size, void* d_ws, size_t ws_size,
                              hipStream_t stream) {
    const float* beta   = (const float*)d_in[0];
    const float* degree = (const float*)d_in[1];
    const int*   A_rows = (const int*)d_in[2];
    const int*   A_cols = (const int*)d_in[3];
    const float* A_vals = (const float*)d_in[4];
    const float* W_in   = (const float*)d_in[5];
    const float* b_in   = (const float*)d_in[6];
    const float* W_mp1  = (const float*)d_in[7];
    const float* W_mp2  = (const float*)d_in[8];
    const float* W_out  = (const float*)d_in[9];
    const float* b_out  = (const float*)d_in[10];
    float* g = (float*)d_out;

    char* ws = (char*)d_ws;
    unsigned short* AH  = (unsigned short*)(ws + OFF_AH);
    unsigned short* A2H = (unsigned short*)(ws + OFF_A2H);
    unsigned short* Bp  = (unsigned short*)(ws + OFF_BP);
    int*    cnt = (int*)(ws + OFF_CNT);
    float2* pc  = (float2*)(ws + OFF_PC);
    int2*   ev  = (int2*)(ws + OFF_EV);

    // prep: Bp pack | pc pack | cnt zero (one launch)
    prep_kernel<<<904, 256, 0, stream>>>(W_mp1, W_mp2, Bp, beta, degree, pc, cnt);

    // XCD-sliced ELL scatter
    scatter_sliced<<<NSLICE * BPS, 256, 0, stream>>>(A_rows, A_cols, A_vals, cnt, ev);

    // AH = A @ relu(x W_in^T + b_in)   (h recomputed per edge)
    spmm_embed_kernel<<<(NP + 3) / 4, 256, 0, stream>>>(cnt, ev, pc, W_in, b_in, AH);
    // A2H = A @ AH
    spmm_gather_kernel<<<(NP + 3) / 4, 256, 0, stream>>>(cnt, ev, AH, A2H);

    mp_out_kernel<<<(NP + 127) / 128, 512, 0, stream>>>(AH, A2H, Bp, W_out, b_out, g);
}